// Round 16
// baseline (790.306 us; speedup 1.0000x reference)
//
#include <hip/hip_runtime.h>
#include <cstdint>
#include <cstddef>

#define NMAX 100000
#define EMAX 300000

typedef __bf16 bf16_t;
typedef __bf16 bf16x8 __attribute__((ext_vector_type(8)));
typedef float f32x4 __attribute__((ext_vector_type(4)));
typedef unsigned int u32;

// Static device scratch (fully rewritten every launch).
__device__ unsigned short g_mega[(size_t)NMAX * 1024];  // [k1|v1|q2|s2] bf16 (token rows)
__device__ unsigned short g_qs [(size_t)NMAX * 512];    // [q1|s1] bf16 (row rows)
__device__ unsigned short g_kv [(size_t)NMAX * 512];    // [k2|v2] bf16 (row rows)
__device__ unsigned short g_eb1[(size_t)EMAX * 256];    // e-proj ph1, CSR-slot order
__device__ unsigned short g_eb2[(size_t)EMAX * 256];    // e-proj ph2, CSR-slot order
__device__ unsigned short g_bfA[(size_t)NMAX * 256];    // token_x bf16 (mega A + ph2 residual)
__device__ unsigned short g_bfB[(size_t)NMAX * 256];    // out_row bf16 (fused1 -> kv2 A)
__device__ unsigned short g_bfW[589824];                // transposed bf16 weights
__device__ float g_bias[2560];                          // concat biases
__device__ int   g_degc[2 * (NMAX + 1)];                // deg ph1 @0, ph2 @NMAX+1
__device__ int   g_rp1 [NMAX + 1];                      // CSR rowptr phase1 (NR)
__device__ int   g_rp2 [NMAX + 1];                      // CSR rowptr phase2 (NT)
__device__ int   g_curc[2 * NMAX];                      // cur ph1 @0, ph2 @NMAX
__device__ int   g_ps1 [EMAX];                          // src per CSR slot, ph1
__device__ int   g_ps2 [EMAX];                          // src per CSR slot, ph2
__device__ int   g_inv1[EMAX];                          // eid -> CSR slot, ph1
__device__ int   g_inv2[EMAX];                          // eid -> CSR slot, ph2
__device__ int   g_bsum[512];

struct P4  { const float* p[4]; };
struct P10 { const float* p[10]; };

__device__ __forceinline__ unsigned short f2bf(float f) {
  unsigned u = __float_as_uint(f);
  return (unsigned short)((u + 0x7fffu + ((u >> 16) & 1u)) >> 16);
}
__device__ __forceinline__ void dec8(uint4 u, float* f) {
  f[0] = __uint_as_float(u.x << 16); f[1] = __uint_as_float(u.x & 0xffff0000u);
  f[2] = __uint_as_float(u.y << 16); f[3] = __uint_as_float(u.y & 0xffff0000u);
  f[4] = __uint_as_float(u.z << 16); f[5] = __uint_as_float(u.z & 0xffff0000u);
  f[6] = __uint_as_float(u.w << 16); f[7] = __uint_as_float(u.w & 0xffff0000u);
}

// f32 -> bf16, 8 elems/thread.
__global__ __launch_bounds__(256) void conv_bf16(const float* __restrict__ in,
                                                 unsigned short* __restrict__ out,
                                                 long long n8) {
  long long i = (long long)blockIdx.x * 256 + threadIdx.x;
  if (i >= n8) return;
  const float4* p = (const float4*)(in + i * 8);
  float4 a = p[0], b = p[1];
  ushort4 lo = make_ushort4(f2bf(a.x), f2bf(a.y), f2bf(a.z), f2bf(a.w));
  ushort4 hi = make_ushort4(f2bf(b.x), f2bf(b.y), f2bf(b.z), f2bf(b.w));
  ushort4* q = (ushort4*)(out + i * 8);
  q[0] = lo; q[1] = hi;
}

// [W0|W1|W2|W3] (each [K,256] f32) -> Wt[NN,K] bf16 transposed.
__global__ __launch_bounds__(256) void wconv4(P4 Ws, unsigned short* __restrict__ Wt,
                                              int K, int NN) {
  int i = blockIdx.x * 256 + threadIdx.x;
  if (i >= NN * K) return;
  int n = i / K, k = i - n * K;
  Wt[i] = f2bf(Ws.p[n >> 8][(size_t)k * 256 + (n & 255)]);
}

// Concatenate 10 bias vectors (256 each) into g_bias.
__global__ __launch_bounds__(256) void bconcat(P10 b, float* __restrict__ out) {
  int i = blockIdx.x * 256 + threadIdx.x;
  if (i < 2560) out[i] = b.p[i >> 8][i & 255];
}

#define GLL16(gp, lp) __builtin_amdgcn_global_load_lds( \
    (const __attribute__((address_space(1))) void*)(gp), \
    (__attribute__((address_space(3))) void*)(lp), 16, 0, 0)

// C[M,NS](bf16) = bf16(A[M,K]) @ Wt^T + bias ; BM2 ? 256x128 : 128x128 tile,
// BK=64, 4 waves, 16x16x32 bf16 MFMA, XOR-swizzled LDS. BM2=true doubles
// MFMA per barrier (drain-bound thin-K GEMMs). A: AF32 reg-staged cvt or
// bf16 global_load_lds. B always global_load_lds. 1-D XCD-swizzled grid
// (r10-verified: FETCH 202->28 MB). inv: CSR-slot row permute on C.
template <int K, int NS, bool AF32, bool BM2>
__global__ __launch_bounds__(256) void gemm_mfma(const void* __restrict__ Av,
                                                 const unsigned short* __restrict__ Bt,
                                                 const float* __restrict__ bias,
                                                 unsigned short* __restrict__ C, int M,
                                                 const int* __restrict__ inv) {
  constexpr int BMT = BM2 ? 256 : 128;
  constexpr int AG  = BM2 ? 8 : 4;     // 8-row A groups per wave
  constexpr int FN  = BM2 ? 8 : 4;     // col fragments per wave
  constexpr int NC  = NS / 128;
  constexpr int LNC = (NC == 8) ? 3 : (NC == 4) ? 2 : 1;
  const int g = blockIdx.x;
  const int r8 = g & 7;
  const int cch = (g >> 3) & (NC - 1);
  const int q8 = g >> (3 + LNC);
  const int mt = q8 * 8 + r8;
  if (mt * BMT >= M) return;
  const int bm = mt * BMT, bn = cch * 128;

  __shared__ __align__(16) unsigned short As[BMT * 64];
  __shared__ __align__(16) unsigned short Bs[128 * 64];
  const int tid = threadIdx.x;
  const int lane = tid & 63, wid = tid >> 6;
  const int wrow = BM2 ? wid * 64 : (wid & 1) * 64;
  const int wcol = BM2 ? 0 : (wid >> 1) * 64;
  const int sr = lane >> 3;
  const int slot = lane & 7;

  f32x4 acc[4][FN] = {};

  for (int k0 = 0; k0 < K; k0 += 64) {
    {
#pragma unroll
      for (int r = 0; r < 4; ++r) {
        int col = (wid * 4 + r) * 8 + sr;
        int kk = k0 + ((slot ^ (col & 7)) << 3);
        GLL16(Bt + (size_t)(bn + col) * K + kk, (unsigned short*)Bs + (size_t)(wid * 4 + r) * 512);
      }
    }
    if constexpr (AF32) {
      const float* Af = (const float*)Av;
#pragma unroll
      for (int r = 0; r < AG; ++r) {
        int row = (wid * AG + r) * 8 + sr;
        int arow = bm + row; if (arow >= M) arow = M - 1;
        int kk = k0 + ((slot ^ (row & 7)) << 3);
        const float* ap = Af + (size_t)arow * K + kk;
        float4 f0 = *(const float4*)ap;
        float4 f1 = *(const float4*)(ap + 4);
        bf16x8 a;
        a[0] = (bf16_t)f0.x; a[1] = (bf16_t)f0.y; a[2] = (bf16_t)f0.z; a[3] = (bf16_t)f0.w;
        a[4] = (bf16_t)f1.x; a[5] = (bf16_t)f1.y; a[6] = (bf16_t)f1.z; a[7] = (bf16_t)f1.w;
        *(bf16x8*)((char*)As + (size_t)row * 128 + (size_t)(slot << 4)) = a;
      }
    } else {
      const unsigned short* Af = (const unsigned short*)Av;
#pragma unroll
      for (int r = 0; r < AG; ++r) {
        int row = (wid * AG + r) * 8 + sr;
        int arow = bm + row; if (arow >= M) arow = M - 1;
        int kk = k0 + ((slot ^ (row & 7)) << 3);
        GLL16(Af + (size_t)arow * K + kk, (unsigned short*)As + (size_t)(wid * AG + r) * 512);
      }
    }
    __syncthreads();
    const char* Ab = (const char*)As;
    const char* Bb = (const char*)Bs;
#pragma unroll
    for (int h = 0; h < 2; ++h) {
      bf16x8 af[4];
      int g2 = (lane >> 4) + h * 4;
#pragma unroll
      for (int fm = 0; fm < 4; ++fm) {
        int row = wrow + fm * 16 + (lane & 15);
        af[fm] = *(const bf16x8*)(Ab + (size_t)row * 128 + ((g2 ^ (row & 7)) << 4));
      }
#pragma unroll
      for (int fn = 0; fn < FN; ++fn) {
        int col = wcol + fn * 16 + (lane & 15);
        bf16x8 bfr = *(const bf16x8*)(Bb + (size_t)col * 128 + ((g2 ^ (col & 7)) << 4));
#pragma unroll
        for (int fm = 0; fm < 4; ++fm)
          acc[fm][fn] = __builtin_amdgcn_mfma_f32_16x16x32_bf16(af[fm], bfr,
                                                                acc[fm][fn], 0, 0, 0);
      }
    }
    __syncthreads();
  }
  float bv[FN];
#pragma unroll
  for (int fn = 0; fn < FN; ++fn) bv[fn] = bias[bn + wcol + fn * 16 + (lane & 15)];
#pragma unroll
  for (int fm = 0; fm < 4; ++fm) {
    int rbase = bm + wrow + fm * 16 + ((lane >> 4) << 2);
#pragma unroll
    for (int j = 0; j < 4; ++j) {
      int row = rbase + j;
      if (row < M) {
        size_t orow = inv ? (size_t)inv[row] : (size_t)row;
        size_t rb = orow * NS + bn + wcol + (lane & 15);
#pragma unroll
        for (int fn = 0; fn < FN; ++fn)
          C[rb + fn * 16] = f2bf(acc[fm][fn][j] + bv[fn]);
      }
    }
  }
}

// ---------------- CSR build (both phases merged) ----------------
__global__ __launch_bounds__(256) void hist2_kernel(const int* __restrict__ ei1,
                                                    const int* __restrict__ ei2,
                                                    int* __restrict__ deg, int E) {
  int i = blockIdx.x * 256 + threadIdx.x;
  if (i < E) atomicAdd(&deg[ei1[E + i]], 1);
  else if (i < 2 * E) atomicAdd(&deg[(NMAX + 1) + ei2[E + (i - E)]], 1);
}

__global__ __launch_bounds__(256) void scan1(const int* __restrict__ deg,
                                             int* __restrict__ rowptr,
                                             int* __restrict__ bsum, int n) {
  __shared__ int ws[4];
  int i = blockIdx.x * 256 + threadIdx.x;
  int v = (i < n) ? deg[i] : 0;
  int lane = threadIdx.x & 63, wid = threadIdx.x >> 6;
  int inc = v;
#pragma unroll
  for (int o = 1; o < 64; o <<= 1) {
    int t = __shfl_up(inc, o);
    if (lane >= o) inc += t;
  }
  if (lane == 63) ws[wid] = inc;
  __syncthreads();
  int woff = 0;
  if (wid > 0) woff += ws[0];
  if (wid > 1) woff += ws[1];
  if (wid > 2) woff += ws[2];
  if (i < n) rowptr[i] = inc - v + woff;
  if (threadIdx.x == 255) bsum[blockIdx.x] = inc + woff;
}

__global__ __launch_bounds__(512) void scan2(int* __restrict__ bsum, int B) {
  __shared__ int s[512];
  int t = threadIdx.x;
  int v = (t < B) ? bsum[t] : 0;
  s[t] = v;
  __syncthreads();
  for (int o = 1; o < 512; o <<= 1) {
    int a = (t >= o) ? s[t - o] : 0;
    __syncthreads();
    s[t] += a;
    __syncthreads();
  }
  if (t < B) bsum[t] = s[t] - v;
}

__global__ __launch_bounds__(256) void scan3(int* __restrict__ rowptr,
                                             const int* __restrict__ bsum,
                                             const int* __restrict__ deg,
                                             int* __restrict__ cur, int n) {
  int i = blockIdx.x * 256 + threadIdx.x;
  if (i < n) {
    int r = rowptr[i] + bsum[blockIdx.x];
    rowptr[i] = r;
    cur[i] = r;
    if (i == n - 1) rowptr[n] = r + deg[i];
  }
}

__global__ __launch_bounds__(256) void scatter2_kernel(const int* __restrict__ ei1,
                                                       const int* __restrict__ ei2,
                                                       int* __restrict__ cur,
                                                       int* __restrict__ ps1,
                                                       int* __restrict__ ps2,
                                                       int* __restrict__ inv1,
                                                       int* __restrict__ inv2, int E) {
  int i = blockIdx.x * 256 + threadIdx.x;
  if (i < E) {
    int s = ei1[i], d = ei1[E + i];
    int pos = atomicAdd(&cur[d], 1);
    ps1[pos] = s;
    inv1[i] = pos;
  } else if (i < 2 * E) {
    int j = i - E;
    int s = ei2[j], d = ei2[E + j];
    int pos = atomicAdd(&cur[NMAX + d], 1);
    ps2[pos] = s;
    inv2[j] = pos;
  }
}

// ---------------- Fused attention + skip + residual + LN (v4) ----------------
// 32 lanes per dst node (8 channels/lane); 8 nodes/block. eb in CSR-slot
// order (sequential reads). Fixed-max softmax (logits ~N(0,0.4), exp-safe);
// exp2f -> single v_exp_f32. Residual x read as bf16 if xb set.
__global__ __launch_bounds__(256) void fused_attn_ln(
    const int* __restrict__ rowptr, const int* __restrict__ psrc,
    const unsigned short* __restrict__ qs, int qs_stride,
    const unsigned short* __restrict__ kv, int kv_stride,
    const unsigned short* __restrict__ eb,
    const float* __restrict__ xf, const unsigned short* __restrict__ xb,
    const float* __restrict__ gamma, const float* __restrict__ beta,
    float* __restrict__ out, unsigned short* __restrict__ out_bf, int N) {
  int node = blockIdx.x * 8 + (threadIdx.x >> 5);
  if (node >= N) return;
  int sub = threadIdx.x & 31;
  int c8 = sub << 3;
  uint4 qu = *(const uint4*)(qs + (size_t)node * qs_stride + c8);
  uint4 su = *(const uint4*)(qs + (size_t)node * qs_stride + 256 + c8);
  size_t base = (size_t)node * 256 + c8;
  float xv[8];
  if (xb) {
    uint4 xu = *(const uint4*)(xb + base);
    dec8(xu, xv);
  } else {
    float4 x0 = *(const float4*)(xf + base);
    float4 x1 = *(const float4*)(xf + base + 4);
    xv[0] = x0.x; xv[1] = x0.y; xv[2] = x0.z; xv[3] = x0.w;
    xv[4] = x1.x; xv[5] = x1.y; xv[6] = x1.z; xv[7] = x1.w;
  }
  float q[8], s[8];
  dec8(qu, q); dec8(su, s);
  float acc[8] = {0.f, 0.f, 0.f, 0.f, 0.f, 0.f, 0.f, 0.f};
  float den = 0.f;
  int beg = rowptr[node], end = rowptr[node + 1];
  int src = (beg < end) ? psrc[beg] : 0;
  uint4 ku = *(const uint4*)(kv + (size_t)src * kv_stride + c8);
  uint4 vu = *(const uint4*)(kv + (size_t)src * kv_stride + 256 + c8);
  uint4 eu = *(const uint4*)(eb + (size_t)((beg < end) ? beg : 0) * 256 + c8);
  for (int p_ = beg; p_ < end; ++p_) {
    int pn = (p_ + 1 < end) ? (p_ + 1) : p_;
    int srcN = psrc[pn];
    uint4 kuN = *(const uint4*)(kv + (size_t)srcN * kv_stride + c8);
    uint4 vuN = *(const uint4*)(kv + (size_t)srcN * kv_stride + 256 + c8);
    uint4 euN = *(const uint4*)(eb + (size_t)pn * 256 + c8);
    float kf[8], vf[8], ef[8];
    dec8(ku, kf); dec8(vu, vf); dec8(eu, ef);
    float p = 0.f;
#pragma unroll
    for (int j = 0; j < 8; ++j) p += q[j] * (kf[j] + ef[j]);
    p += __shfl_xor(p, 1); p += __shfl_xor(p, 2); p += __shfl_xor(p, 4);
    float w = exp2f(p * (0.125f * 1.44269504f));   // fixed-max softmax
    den += w;
#pragma unroll
    for (int j = 0; j < 8; ++j) acc[j] += w * (vf[j] + ef[j]);
    ku = kuN; vu = vuN; eu = euN;
  }
  float inv = (den > 0.f) ? 1.0f / den : 0.f;
  float val[8];
#pragma unroll
  for (int j = 0; j < 8; ++j) val[j] = xv[j] + s[j] + acc[j] * inv;
  float t = 0.f;
#pragma unroll
  for (int j = 0; j < 8; ++j) t += val[j];
#pragma unroll
  for (int o = 1; o < 32; o <<= 1) t += __shfl_xor(t, o);
  float mean = t * (1.0f / 256.0f);
  float d[8], ss = 0.f;
#pragma unroll
  for (int j = 0; j < 8; ++j) { d[j] = val[j] - mean; ss += d[j] * d[j]; }
#pragma unroll
  for (int o = 1; o < 32; o <<= 1) ss += __shfl_xor(ss, o);
  float rstd = rsqrtf(ss * (1.0f / 256.0f) + 1e-5f);
  float4 g0 = *(const float4*)(gamma + c8);
  float4 g1 = *(const float4*)(gamma + c8 + 4);
  float4 b0 = *(const float4*)(beta + c8);
  float4 b1 = *(const float4*)(beta + c8 + 4);
  float o8[8];
  o8[0] = d[0] * rstd * g0.x + b0.x; o8[1] = d[1] * rstd * g0.y + b0.y;
  o8[2] = d[2] * rstd * g0.z + b0.z; o8[3] = d[3] * rstd * g0.w + b0.w;
  o8[4] = d[4] * rstd * g1.x + b1.x; o8[5] = d[5] * rstd * g1.y + b1.y;
  o8[6] = d[6] * rstd * g1.z + b1.z; o8[7] = d[7] * rstd * g1.w + b1.w;
  *(float4*)(out + base)     = make_float4(o8[0], o8[1], o8[2], o8[3]);
  *(float4*)(out + base + 4) = make_float4(o8[4], o8[5], o8[6], o8[7]);
  if (out_bf) {
    uint4 ob;
    ob.x = (u32)f2bf(o8[0]) | ((u32)f2bf(o8[1]) << 16);
    ob.y = (u32)f2bf(o8[2]) | ((u32)f2bf(o8[3]) << 16);
    ob.z = (u32)f2bf(o8[4]) | ((u32)f2bf(o8[5]) << 16);
    ob.w = (u32)f2bf(o8[6]) | ((u32)f2bf(o8[7]) << 16);
    *(uint4*)(out_bf + base) = ob;
  }
}

extern "C" void kernel_launch(void* const* d_in, const int* in_sizes, int n_in,
                              void* d_out, int out_size, void* d_ws, size_t ws_size,
                              hipStream_t stream) {
  const float* row_x   = (const float*)d_in[0];
  const float* token_x = (const float*)d_in[1];
  const int*   ei1     = (const int*)d_in[2];    // int32 (JAX x64 disabled)
  const float* ea1     = (const float*)d_in[3];
  const int*   ei2     = (const int*)d_in[4];
  const float* ea2     = (const float*)d_in[5];

  const float* W1q = (const float*)d_in[6];  const float* b1q = (const float*)d_in[7];
  const float* W1k = (const float*)d_in[8];  const float* b1k = (const float*)d_in[9];
  const float* W1v = (const float*)d_in[10]; const float* b1v = (const float*)d_in[11];
  const float* W1e = (const float*)d_in[12]; const float* b1e = (const float*)d_in[13];
  const float* W1s = (const float*)d_in[14]; const float* b1s = (const float*)d_in[15];
  const float* W2q = (const float*)d_in[16]; const float* b2q = (const float*)d_in[17];
  const float* W2k = (const float*)d_in[18]; const float* b2k = (const float*)d_in[19];
  const float* W2v = (const float*)d_in[20]; const float* b2v = (const float*)d_in[21];
  const float* W2e = (const float*)d_in[22]; const float* b2e = (const float*)d_in[23];
  const float* W2s = (const float*)d_in[24]; const float* b2s = (const float*)d_in[25];
  const float* row_gamma   = (const float*)d_in[26];
  const float* row_beta    = (const float*)d_in[27];
  const float* token_gamma = (const float*)d_in[28];
  const float* token_beta  = (const float*)d_in[29];

  const int NR = in_sizes[0] / 256;   // 20000
  const int NT = in_sizes[1] / 256;   // 100000
  const int E  = in_sizes[2] / 2;     // 300000

  float* out_row = (float*)d_out;
  float* out_tok = (float*)d_out + (long long)NR * 256;

  void *pmega_, *pqs_, *pkv_, *peb1_, *peb2_, *pbfA_, *pbfB_, *pbfW_, *pbias_,
       *pdeg_, *prp1_, *prp2_, *pcur_, *pps1_, *pps2_, *pinv1_, *pinv2_, *pbs_;
  hipGetSymbolAddress(&pmega_, HIP_SYMBOL(g_mega));
  hipGetSymbolAddress(&pqs_,   HIP_SYMBOL(g_qs));
  hipGetSymbolAddress(&pkv_,   HIP_SYMBOL(g_kv));
  hipGetSymbolAddress(&peb1_,  HIP_SYMBOL(g_eb1));
  hipGetSymbolAddress(&peb2_,  HIP_SYMBOL(g_eb2));
  hipGetSymbolAddress(&pbfA_,  HIP_SYMBOL(g_bfA));
  hipGetSymbolAddress(&pbfB_,  HIP_SYMBOL(g_bfB));
  hipGetSymbolAddress(&pbfW_,  HIP_SYMBOL(g_bfW));
  hipGetSymbolAddress(&pbias_, HIP_SYMBOL(g_bias));
  hipGetSymbolAddress(&pdeg_,  HIP_SYMBOL(g_degc));
  hipGetSymbolAddress(&prp1_,  HIP_SYMBOL(g_rp1));
  hipGetSymbolAddress(&prp2_,  HIP_SYMBOL(g_rp2));
  hipGetSymbolAddress(&pcur_,  HIP_SYMBOL(g_curc));
  hipGetSymbolAddress(&pps1_,  HIP_SYMBOL(g_ps1));
  hipGetSymbolAddress(&pps2_,  HIP_SYMBOL(g_ps2));
  hipGetSymbolAddress(&pinv1_, HIP_SYMBOL(g_inv1));
  hipGetSymbolAddress(&pinv2_, HIP_SYMBOL(g_inv2));
  hipGetSymbolAddress(&pbs_,   HIP_SYMBOL(g_bsum));
  unsigned short* mega = (unsigned short*)pmega_;
  unsigned short* qs   = (unsigned short*)pqs_;
  unsigned short* kv   = (unsigned short*)pkv_;
  unsigned short* eb1  = (unsigned short*)peb1_;
  unsigned short* eb2  = (unsigned short*)peb2_;
  unsigned short* bfA  = (unsigned short*)pbfA_;
  unsigned short* bfB  = (unsigned short*)pbfB_;
  unsigned short* bfW  = (unsigned short*)pbfW_;
  float* gbias = (float*)pbias_;
  int*   deg   = (int*)pdeg_;
  int*   rp1   = (int*)prp1_;
  int*   rp2   = (int*)prp2_;
  int*   cur   = (int*)pcur_;
  int*   ps1   = (int*)pps1_;
  int*   ps2   = (int*)pps2_;
  int*   inv1  = (int*)pinv1_;
  int*   inv2  = (int*)pinv2_;
  int*   bsum  = (int*)pbs_;

  unsigned short* Wmega = bfW + 0;
  unsigned short* Wqs1  = bfW + 262144;
  unsigned short* Wkv2  = bfW + 393216;
  unsigned short* We1   = bfW + 524288;
  unsigned short* We2   = bfW + 557056;
  wconv4<<<1024, 256, 0, stream>>>(P4{{W1k, W1v, W2q, W2s}}, Wmega, 256, 1024);
  wconv4<<<512, 256, 0, stream>>>(P4{{W1q, W1s, nullptr, nullptr}}, Wqs1, 256, 512);
  wconv4<<<512, 256, 0, stream>>>(P4{{W2k, W2v, nullptr, nullptr}}, Wkv2, 256, 512);
  wconv4<<<128, 256, 0, stream>>>(P4{{W1e, nullptr, nullptr, nullptr}}, We1, 128, 256);
  wconv4<<<128, 256, 0, stream>>>(P4{{W2e, nullptr, nullptr, nullptr}}, We2, 128, 256);
  P10 bp{{b1k, b1v, b2q, b2s, b1q, b1s, b2k, b2v, b1e, b2e}};
  bconcat<<<10, 256, 0, stream>>>(bp, gbias);

  // token_x f32 -> bf16 (mega's A + ph2 residual).
  conv_bf16<<<(int)(((long long)NT * 32 + 255) / 256), 256, 0, stream>>>(
      token_x, bfA, (long long)NT * 32);

  const int e2grid = (2 * E + 255) / 256;

  // ---------------- CSR build (merged phases) ----------------
  hipMemsetAsync(deg, 0, (size_t)(2 * (NMAX + 1)) * sizeof(int), stream);
  hist2_kernel<<<e2grid, 256, 0, stream>>>(ei1, ei2, deg, E);
  {
    int B1 = (NR + 255) / 256;
    scan1<<<B1, 256, 0, stream>>>(deg, rp1, bsum, NR);
    scan2<<<1, 512, 0, stream>>>(bsum, B1);
    scan3<<<B1, 256, 0, stream>>>(rp1, bsum, deg, cur, NR);
    int B2 = (NT + 255) / 256;
    scan1<<<B2, 256, 0, stream>>>(deg + NMAX + 1, rp2, bsum, NT);
    scan2<<<1, 512, 0, stream>>>(bsum, B2);
    scan3<<<B2, 256, 0, stream>>>(rp2, bsum, deg + NMAX + 1, cur + NMAX, NT);
  }
  scatter2_kernel<<<e2grid, 256, 0, stream>>>(ei1, ei2, cur, ps1, ps2, inv1, inv2, E);

  // Swizzled 1-D grid size for tile height BMT: ceil(nm/8)*8 * NC.
  auto swgrid = [](int M, int NC, int BMT) {
    int nm = (M + BMT - 1) / BMT;
    return (((nm + 7) / 8) * 8) * NC;
  };

  // ---------------- Projection GEMMs ----------------
  gemm_mfma<256, 1024, false, true><<<swgrid(NT, 8, 256), 256, 0, stream>>>(
      bfA, Wmega, gbias + 0, mega, NT, nullptr);        // [k1|v1|q2|s2], BM=256
  gemm_mfma<256, 512, true, false><<<swgrid(NR, 4, 128), 256, 0, stream>>>(
      row_x, Wqs1, gbias + 1024, qs, NR, nullptr);      // [q1|s1]
  gemm_mfma<128, 256, true, true><<<swgrid(E, 2, 256), 256, 0, stream>>>(
      ea1, We1, gbias + 2048, eb1, E, inv1);            // CSR-slot order, BM=256
  gemm_mfma<128, 256, true, true><<<swgrid(E, 2, 256), 256, 0, stream>>>(
      ea2, We2, gbias + 2304, eb2, E, inv2);            // CSR-slot order, BM=256

  // ---------------- Phase 1: t2r ----------------
  fused_attn_ln<<<(NR + 7) / 8, 256, 0, stream>>>(rp1, ps1,
                                                  qs, 512, mega, 1024, eb1,
                                                  row_x, nullptr,
                                                  row_gamma, row_beta,
                                                  out_row, bfB, NR);

  // ---------------- Phase 2: r2t ----------------
  gemm_mfma<256, 512, false, false><<<swgrid(NR, 4, 128), 256, 0, stream>>>(
      bfB, Wkv2, gbias + 1536, kv, NR, nullptr);        // [k2|v2]
  fused_attn_ln<<<(NT + 7) / 8, 256, 0, stream>>>(rp2, ps2,
                                                  mega + 512, 1024, kv, 512, eb2,
                                                  nullptr, bfA,
                                                  token_gamma, token_beta,
                                                  out_tok, nullptr, NT);
}

// Round 17
// 593.511 us; speedup vs baseline: 1.3316x; 1.3316x over previous
//
#include <hip/hip_runtime.h>
#include <cstdint>
#include <cstddef>

#define NMAX 100000
#define EMAX 300000

typedef __bf16 bf16_t;
typedef __bf16 bf16x8 __attribute__((ext_vector_type(8)));
typedef float f32x4 __attribute__((ext_vector_type(4)));
typedef unsigned int u32;

// Static device scratch (fully rewritten every launch).
__device__ unsigned short g_mega[(size_t)NMAX * 1024];  // [k1|v1|q2|s2] bf16 (token rows)
__device__ unsigned short g_qs [(size_t)NMAX * 512];    // [q1|s1] bf16 (row rows)
__device__ unsigned short g_kv [(size_t)NMAX * 512];    // [k2|v2] bf16 (row rows)
__device__ unsigned short g_eb1[(size_t)EMAX * 256];    // e-proj ph1, CSR-slot order
__device__ unsigned short g_eb2[(size_t)EMAX * 256];    // e-proj ph2, CSR-slot order
__device__ unsigned short g_bfA[(size_t)NMAX * 256];    // token_x bf16 (mega A + ph2 residual)
__device__ unsigned short g_bfB[(size_t)NMAX * 256];    // out_row bf16 (fused1 -> kv2 A)
__device__ unsigned short g_bfW[589824];                // transposed bf16 weights
__device__ float g_bias[2560];                          // concat biases
__device__ int   g_degc[2 * (NMAX + 1)];                // deg ph1 @0, ph2 @NMAX+1
__device__ int   g_rp1 [NMAX + 1];                      // CSR rowptr phase1 (NR)
__device__ int   g_rp2 [NMAX + 1];                      // CSR rowptr phase2 (NT)
__device__ int   g_curc[2 * NMAX];                      // cur ph1 @0, ph2 @NMAX
__device__ int   g_ps1 [EMAX];                          // src per CSR slot, ph1
__device__ int   g_ps2 [EMAX];                          // src per CSR slot, ph2
__device__ int   g_inv1[EMAX];                          // eid -> CSR slot, ph1
__device__ int   g_inv2[EMAX];                          // eid -> CSR slot, ph2
__device__ int   g_bsum[512];

struct P20 { const float* w[10]; const float* b[10]; };

__device__ __forceinline__ unsigned short f2bf(float f) {
  unsigned u = __float_as_uint(f);
  return (unsigned short)((u + 0x7fffu + ((u >> 16) & 1u)) >> 16);
}
__device__ __forceinline__ void dec8(uint4 u, float* f) {
  f[0] = __uint_as_float(u.x << 16); f[1] = __uint_as_float(u.x & 0xffff0000u);
  f[2] = __uint_as_float(u.y << 16); f[3] = __uint_as_float(u.y & 0xffff0000u);
  f[4] = __uint_as_float(u.z << 16); f[5] = __uint_as_float(u.z & 0xffff0000u);
  f[6] = __uint_as_float(u.w << 16); f[7] = __uint_as_float(u.w & 0xffff0000u);
}

// f32 -> bf16, 8 elems/thread.
__global__ __launch_bounds__(256) void conv_bf16(const float* __restrict__ in,
                                                 unsigned short* __restrict__ out,
                                                 long long n8) {
  long long i = (long long)blockIdx.x * 256 + threadIdx.x;
  if (i >= n8) return;
  const float4* p = (const float4*)(in + i * 8);
  float4 a = p[0], b = p[1];
  ushort4 lo = make_ushort4(f2bf(a.x), f2bf(a.y), f2bf(a.z), f2bf(a.w));
  ushort4 hi = make_ushort4(f2bf(b.x), f2bf(b.y), f2bf(b.z), f2bf(b.w));
  ushort4* q = (ushort4*)(out + i * 8);
  q[0] = lo; q[1] = hi;
}

// One-shot weight prep: all 10 transposed bf16 weight blocks + concat biases.
// Layout in g_bfW (elements): mega[0,262144) {W1k,W1v,W2q,W2s};
// qs1[262144,393216) {W1q,W1s}; kv2[393216,524288) {W2k,W2v};
// e1[524288,557056) {W1e}; e2[557056,589824) {W2e}. Bias at tail indices.
__global__ __launch_bounds__(256) void prep_weights(P20 P,
                                                    unsigned short* __restrict__ Wt,
                                                    float* __restrict__ gbias) {
  int i = blockIdx.x * 256 + threadIdx.x;
  if (i < 589824) {
    int s = (i < 262144) ? 0 : (i < 393216) ? 1 : (i < 524288) ? 2
          : (i < 557056) ? 3 : 4;
    const int base[5] = {0, 262144, 393216, 524288, 557056};
    const int ksh[5]  = {8, 8, 8, 7, 7};        // log2(K)
    const int wb[5]   = {0, 4, 6, 8, 9};
    int local = i - base[s];
    int n = local >> ksh[s];
    int k = local & ((1 << ksh[s]) - 1);
    Wt[i] = f2bf(P.w[wb[s] + (n >> 8)][(size_t)k * 256 + (n & 255)]);
  } else if (i < 592384) {
    int j = i - 589824;
    gbias[j] = P.b[j >> 8][j & 255];
  }
}

#define GLL16(gp, lp) __builtin_amdgcn_global_load_lds( \
    (const __attribute__((address_space(1))) void*)(gp), \
    (__attribute__((address_space(3))) void*)(lp), 16, 0, 0)

// C[M,NS](bf16) = bf16(A[M,K]) @ Wt^T + bias ; 128x128 tile, BK=64, 4 waves,
// 16x16x32 bf16 MFMA, XOR-swizzled LDS. A: AF32 reg-staged cvt (win for
// K=128) or bf16 global_load_lds (win for K=256). B always global_load_lds.
// 1-D XCD-swizzled grid (r10: FETCH 202->28 MB). 128^2 tile is the measured
// optimum: co-resident blocks hide the per-K-step barrier drain (r16: BM=256
// VGPR 156 -> occupancy 10% -> 1.5x SLOWER). inv: CSR-slot row permute on C.
template <int K, int NS, bool AF32>
__global__ __launch_bounds__(256) void gemm_mfma(const void* __restrict__ Av,
                                                 const unsigned short* __restrict__ Bt,
                                                 const float* __restrict__ bias,
                                                 unsigned short* __restrict__ C, int M,
                                                 const int* __restrict__ inv) {
  constexpr int NC  = NS / 128;
  constexpr int LNC = (NC == 8) ? 3 : (NC == 4) ? 2 : 1;
  const int g = blockIdx.x;
  const int r8 = g & 7;
  const int cch = (g >> 3) & (NC - 1);
  const int q8 = g >> (3 + LNC);
  const int mt = q8 * 8 + r8;
  if (mt * 128 >= M) return;
  const int bm = mt * 128, bn = cch * 128;

  __shared__ __align__(16) unsigned short As[128 * 64];
  __shared__ __align__(16) unsigned short Bs[128 * 64];
  const int tid = threadIdx.x;
  const int lane = tid & 63, wid = tid >> 6;
  const int wrow = (wid & 1) * 64, wcol = (wid >> 1) * 64;
  const int sr = lane >> 3;
  const int slot = lane & 7;

  f32x4 acc[4][4] = {};

  for (int k0 = 0; k0 < K; k0 += 64) {
    {
#pragma unroll
      for (int r = 0; r < 4; ++r) {
        int col = (wid * 4 + r) * 8 + sr;
        int kk = k0 + ((slot ^ (col & 7)) << 3);
        GLL16(Bt + (size_t)(bn + col) * K + kk, (unsigned short*)Bs + (size_t)(wid * 4 + r) * 512);
      }
    }
    if constexpr (AF32) {
      const float* Af = (const float*)Av;
#pragma unroll
      for (int r = 0; r < 4; ++r) {
        int row = (wid * 4 + r) * 8 + sr;
        int arow = bm + row; if (arow >= M) arow = M - 1;
        int kk = k0 + ((slot ^ (row & 7)) << 3);
        const float* ap = Af + (size_t)arow * K + kk;
        float4 f0 = *(const float4*)ap;
        float4 f1 = *(const float4*)(ap + 4);
        bf16x8 a;
        a[0] = (bf16_t)f0.x; a[1] = (bf16_t)f0.y; a[2] = (bf16_t)f0.z; a[3] = (bf16_t)f0.w;
        a[4] = (bf16_t)f1.x; a[5] = (bf16_t)f1.y; a[6] = (bf16_t)f1.z; a[7] = (bf16_t)f1.w;
        *(bf16x8*)((char*)As + (size_t)row * 128 + (size_t)(slot << 4)) = a;
      }
    } else {
      const unsigned short* Af = (const unsigned short*)Av;
#pragma unroll
      for (int r = 0; r < 4; ++r) {
        int row = (wid * 4 + r) * 8 + sr;
        int arow = bm + row; if (arow >= M) arow = M - 1;
        int kk = k0 + ((slot ^ (row & 7)) << 3);
        GLL16(Af + (size_t)arow * K + kk, (unsigned short*)As + (size_t)(wid * 4 + r) * 512);
      }
    }
    __syncthreads();
    const char* Ab = (const char*)As;
    const char* Bb = (const char*)Bs;
#pragma unroll
    for (int h = 0; h < 2; ++h) {
      bf16x8 af[4], bfr[4];
      int g2 = (lane >> 4) + h * 4;
#pragma unroll
      for (int fm = 0; fm < 4; ++fm) {
        int row = wrow + fm * 16 + (lane & 15);
        af[fm] = *(const bf16x8*)(Ab + row * 128 + ((g2 ^ (row & 7)) << 4));
      }
#pragma unroll
      for (int fn = 0; fn < 4; ++fn) {
        int col = wcol + fn * 16 + (lane & 15);
        bfr[fn] = *(const bf16x8*)(Bb + col * 128 + ((g2 ^ (col & 7)) << 4));
      }
#pragma unroll
      for (int fm = 0; fm < 4; ++fm)
#pragma unroll
        for (int fn = 0; fn < 4; ++fn)
          acc[fm][fn] = __builtin_amdgcn_mfma_f32_16x16x32_bf16(af[fm], bfr[fn],
                                                                acc[fm][fn], 0, 0, 0);
    }
    __syncthreads();
  }
  float bv[4];
#pragma unroll
  for (int fn = 0; fn < 4; ++fn) bv[fn] = bias[bn + wcol + fn * 16 + (lane & 15)];
#pragma unroll
  for (int fm = 0; fm < 4; ++fm) {
    int rbase = bm + wrow + fm * 16 + ((lane >> 4) << 2);
#pragma unroll
    for (int j = 0; j < 4; ++j) {
      int row = rbase + j;
      if (row < M) {
        size_t orow = inv ? (size_t)inv[row] : (size_t)row;
        size_t rb = orow * NS + bn + wcol + (lane & 15);
#pragma unroll
        for (int fn = 0; fn < 4; ++fn)
          C[rb + fn * 16] = f2bf(acc[fm][fn][j] + bv[fn]);
      }
    }
  }
}

// ---------------- CSR build (both phases merged) ----------------
__global__ __launch_bounds__(256) void hist2_kernel(const int* __restrict__ ei1,
                                                    const int* __restrict__ ei2,
                                                    int* __restrict__ deg, int E) {
  int i = blockIdx.x * 256 + threadIdx.x;
  if (i < E) atomicAdd(&deg[ei1[E + i]], 1);
  else if (i < 2 * E) atomicAdd(&deg[(NMAX + 1) + ei2[E + (i - E)]], 1);
}

__global__ __launch_bounds__(256) void scan1(const int* __restrict__ deg,
                                             int* __restrict__ rowptr,
                                             int* __restrict__ bsum, int n) {
  __shared__ int ws[4];
  int i = blockIdx.x * 256 + threadIdx.x;
  int v = (i < n) ? deg[i] : 0;
  int lane = threadIdx.x & 63, wid = threadIdx.x >> 6;
  int inc = v;
#pragma unroll
  for (int o = 1; o < 64; o <<= 1) {
    int t = __shfl_up(inc, o);
    if (lane >= o) inc += t;
  }
  if (lane == 63) ws[wid] = inc;
  __syncthreads();
  int woff = 0;
  if (wid > 0) woff += ws[0];
  if (wid > 1) woff += ws[1];
  if (wid > 2) woff += ws[2];
  if (i < n) rowptr[i] = inc - v + woff;
  if (threadIdx.x == 255) bsum[blockIdx.x] = inc + woff;
}

__global__ __launch_bounds__(512) void scan2(int* __restrict__ bsum, int B) {
  __shared__ int s[512];
  int t = threadIdx.x;
  int v = (t < B) ? bsum[t] : 0;
  s[t] = v;
  __syncthreads();
  for (int o = 1; o < 512; o <<= 1) {
    int a = (t >= o) ? s[t - o] : 0;
    __syncthreads();
    s[t] += a;
    __syncthreads();
  }
  if (t < B) bsum[t] = s[t] - v;
}

__global__ __launch_bounds__(256) void scan3(int* __restrict__ rowptr,
                                             const int* __restrict__ bsum,
                                             const int* __restrict__ deg,
                                             int* __restrict__ cur, int n) {
  int i = blockIdx.x * 256 + threadIdx.x;
  if (i < n) {
    int r = rowptr[i] + bsum[blockIdx.x];
    rowptr[i] = r;
    cur[i] = r;
    if (i == n - 1) rowptr[n] = r + deg[i];
  }
}

__global__ __launch_bounds__(256) void scatter2_kernel(const int* __restrict__ ei1,
                                                       const int* __restrict__ ei2,
                                                       int* __restrict__ cur,
                                                       int* __restrict__ ps1,
                                                       int* __restrict__ ps2,
                                                       int* __restrict__ inv1,
                                                       int* __restrict__ inv2, int E) {
  int i = blockIdx.x * 256 + threadIdx.x;
  if (i < E) {
    int s = ei1[i], d = ei1[E + i];
    int pos = atomicAdd(&cur[d], 1);
    ps1[pos] = s;
    inv1[i] = pos;
  } else if (i < 2 * E) {
    int j = i - E;
    int s = ei2[j], d = ei2[E + j];
    int pos = atomicAdd(&cur[NMAX + d], 1);
    ps2[pos] = s;
    inv2[j] = pos;
  }
}

// ---------------- Fused attention + skip + residual + LN (v4) ----------------
// 32 lanes per dst node (8 channels/lane); 8 nodes/block. eb in CSR-slot
// order (sequential reads). Fixed-max softmax (logits ~N(0,0.4), exp-safe);
// exp2f -> single v_exp_f32. Residual x read as bf16 if xb set.
__global__ __launch_bounds__(256) void fused_attn_ln(
    const int* __restrict__ rowptr, const int* __restrict__ psrc,
    const unsigned short* __restrict__ qs, int qs_stride,
    const unsigned short* __restrict__ kv, int kv_stride,
    const unsigned short* __restrict__ eb,
    const float* __restrict__ xf, const unsigned short* __restrict__ xb,
    const float* __restrict__ gamma, const float* __restrict__ beta,
    float* __restrict__ out, unsigned short* __restrict__ out_bf, int N) {
  int node = blockIdx.x * 8 + (threadIdx.x >> 5);
  if (node >= N) return;
  int sub = threadIdx.x & 31;
  int c8 = sub << 3;
  uint4 qu = *(const uint4*)(qs + (size_t)node * qs_stride + c8);
  uint4 su = *(const uint4*)(qs + (size_t)node * qs_stride + 256 + c8);
  size_t base = (size_t)node * 256 + c8;
  float xv[8];
  if (xb) {
    uint4 xu = *(const uint4*)(xb + base);
    dec8(xu, xv);
  } else {
    float4 x0 = *(const float4*)(xf + base);
    float4 x1 = *(const float4*)(xf + base + 4);
    xv[0] = x0.x; xv[1] = x0.y; xv[2] = x0.z; xv[3] = x0.w;
    xv[4] = x1.x; xv[5] = x1.y; xv[6] = x1.z; xv[7] = x1.w;
  }
  float q[8], s[8];
  dec8(qu, q); dec8(su, s);
  float acc[8] = {0.f, 0.f, 0.f, 0.f, 0.f, 0.f, 0.f, 0.f};
  float den = 0.f;
  int beg = rowptr[node], end = rowptr[node + 1];
  int src = (beg < end) ? psrc[beg] : 0;
  uint4 ku = *(const uint4*)(kv + (size_t)src * kv_stride + c8);
  uint4 vu = *(const uint4*)(kv + (size_t)src * kv_stride + 256 + c8);
  uint4 eu = *(const uint4*)(eb + (size_t)((beg < end) ? beg : 0) * 256 + c8);
  for (int p_ = beg; p_ < end; ++p_) {
    int pn = (p_ + 1 < end) ? (p_ + 1) : p_;
    int srcN = psrc[pn];
    uint4 kuN = *(const uint4*)(kv + (size_t)srcN * kv_stride + c8);
    uint4 vuN = *(const uint4*)(kv + (size_t)srcN * kv_stride + 256 + c8);
    uint4 euN = *(const uint4*)(eb + (size_t)pn * 256 + c8);
    float kf[8], vf[8], ef[8];
    dec8(ku, kf); dec8(vu, vf); dec8(eu, ef);
    float p = 0.f;
#pragma unroll
    for (int j = 0; j < 8; ++j) p += q[j] * (kf[j] + ef[j]);
    p += __shfl_xor(p, 1); p += __shfl_xor(p, 2); p += __shfl_xor(p, 4);
    float w = exp2f(p * (0.125f * 1.44269504f));   // fixed-max softmax
    den += w;
#pragma unroll
    for (int j = 0; j < 8; ++j) acc[j] += w * (vf[j] + ef[j]);
    ku = kuN; vu = vuN; eu = euN;
  }
  float inv = (den > 0.f) ? 1.0f / den : 0.f;
  float val[8];
#pragma unroll
  for (int j = 0; j < 8; ++j) val[j] = xv[j] + s[j] + acc[j] * inv;
  float t = 0.f;
#pragma unroll
  for (int j = 0; j < 8; ++j) t += val[j];
#pragma unroll
  for (int o = 1; o < 32; o <<= 1) t += __shfl_xor(t, o);
  float mean = t * (1.0f / 256.0f);
  float d[8], ss = 0.f;
#pragma unroll
  for (int j = 0; j < 8; ++j) { d[j] = val[j] - mean; ss += d[j] * d[j]; }
#pragma unroll
  for (int o = 1; o < 32; o <<= 1) ss += __shfl_xor(ss, o);
  float rstd = rsqrtf(ss * (1.0f / 256.0f) + 1e-5f);
  float4 g0 = *(const float4*)(gamma + c8);
  float4 g1 = *(const float4*)(gamma + c8 + 4);
  float4 b0 = *(const float4*)(beta + c8);
  float4 b1 = *(const float4*)(beta + c8 + 4);
  float o8[8];
  o8[0] = d[0] * rstd * g0.x + b0.x; o8[1] = d[1] * rstd * g0.y + b0.y;
  o8[2] = d[2] * rstd * g0.z + b0.z; o8[3] = d[3] * rstd * g0.w + b0.w;
  o8[4] = d[4] * rstd * g1.x + b1.x; o8[5] = d[5] * rstd * g1.y + b1.y;
  o8[6] = d[6] * rstd * g1.z + b1.z; o8[7] = d[7] * rstd * g1.w + b1.w;
  *(float4*)(out + base)     = make_float4(o8[0], o8[1], o8[2], o8[3]);
  *(float4*)(out + base + 4) = make_float4(o8[4], o8[5], o8[6], o8[7]);
  if (out_bf) {
    uint4 ob;
    ob.x = (u32)f2bf(o8[0]) | ((u32)f2bf(o8[1]) << 16);
    ob.y = (u32)f2bf(o8[2]) | ((u32)f2bf(o8[3]) << 16);
    ob.z = (u32)f2bf(o8[4]) | ((u32)f2bf(o8[5]) << 16);
    ob.w = (u32)f2bf(o8[6]) | ((u32)f2bf(o8[7]) << 16);
    *(uint4*)(out_bf + base) = ob;
  }
}

extern "C" void kernel_launch(void* const* d_in, const int* in_sizes, int n_in,
                              void* d_out, int out_size, void* d_ws, size_t ws_size,
                              hipStream_t stream) {
  const float* row_x   = (const float*)d_in[0];
  const float* token_x = (const float*)d_in[1];
  const int*   ei1     = (const int*)d_in[2];    // int32 (JAX x64 disabled)
  const float* ea1     = (const float*)d_in[3];
  const int*   ei2     = (const int*)d_in[4];
  const float* ea2     = (const float*)d_in[5];

  const float* W1q = (const float*)d_in[6];  const float* b1q = (const float*)d_in[7];
  const float* W1k = (const float*)d_in[8];  const float* b1k = (const float*)d_in[9];
  const float* W1v = (const float*)d_in[10]; const float* b1v = (const float*)d_in[11];
  const float* W1e = (const float*)d_in[12]; const float* b1e = (const float*)d_in[13];
  const float* W1s = (const float*)d_in[14]; const float* b1s = (const float*)d_in[15];
  const float* W2q = (const float*)d_in[16]; const float* b2q = (const float*)d_in[17];
  const float* W2k = (const float*)d_in[18]; const float* b2k = (const float*)d_in[19];
  const float* W2v = (const float*)d_in[20]; const float* b2v = (const float*)d_in[21];
  const float* W2e = (const float*)d_in[22]; const float* b2e = (const float*)d_in[23];
  const float* W2s = (const float*)d_in[24]; const float* b2s = (const float*)d_in[25];
  const float* row_gamma   = (const float*)d_in[26];
  const float* row_beta    = (const float*)d_in[27];
  const float* token_gamma = (const float*)d_in[28];
  const float* token_beta  = (const float*)d_in[29];

  const int NR = in_sizes[0] / 256;   // 20000
  const int NT = in_sizes[1] / 256;   // 100000
  const int E  = in_sizes[2] / 2;     // 300000

  float* out_row = (float*)d_out;
  float* out_tok = (float*)d_out + (long long)NR * 256;

  void *pmega_, *pqs_, *pkv_, *peb1_, *peb2_, *pbfA_, *pbfB_, *pbfW_, *pbias_,
       *pdeg_, *prp1_, *prp2_, *pcur_, *pps1_, *pps2_, *pinv1_, *pinv2_, *pbs_;
  hipGetSymbolAddress(&pmega_, HIP_SYMBOL(g_mega));
  hipGetSymbolAddress(&pqs_,   HIP_SYMBOL(g_qs));
  hipGetSymbolAddress(&pkv_,   HIP_SYMBOL(g_kv));
  hipGetSymbolAddress(&peb1_,  HIP_SYMBOL(g_eb1));
  hipGetSymbolAddress(&peb2_,  HIP_SYMBOL(g_eb2));
  hipGetSymbolAddress(&pbfA_,  HIP_SYMBOL(g_bfA));
  hipGetSymbolAddress(&pbfB_,  HIP_SYMBOL(g_bfB));
  hipGetSymbolAddress(&pbfW_,  HIP_SYMBOL(g_bfW));
  hipGetSymbolAddress(&pbias_, HIP_SYMBOL(g_bias));
  hipGetSymbolAddress(&pdeg_,  HIP_SYMBOL(g_degc));
  hipGetSymbolAddress(&prp1_,  HIP_SYMBOL(g_rp1));
  hipGetSymbolAddress(&prp2_,  HIP_SYMBOL(g_rp2));
  hipGetSymbolAddress(&pcur_,  HIP_SYMBOL(g_curc));
  hipGetSymbolAddress(&pps1_,  HIP_SYMBOL(g_ps1));
  hipGetSymbolAddress(&pps2_,  HIP_SYMBOL(g_ps2));
  hipGetSymbolAddress(&pinv1_, HIP_SYMBOL(g_inv1));
  hipGetSymbolAddress(&pinv2_, HIP_SYMBOL(g_inv2));
  hipGetSymbolAddress(&pbs_,   HIP_SYMBOL(g_bsum));
  unsigned short* mega = (unsigned short*)pmega_;
  unsigned short* qs   = (unsigned short*)pqs_;
  unsigned short* kv   = (unsigned short*)pkv_;
  unsigned short* eb1  = (unsigned short*)peb1_;
  unsigned short* eb2  = (unsigned short*)peb2_;
  unsigned short* bfA  = (unsigned short*)pbfA_;
  unsigned short* bfB  = (unsigned short*)pbfB_;
  unsigned short* bfW  = (unsigned short*)pbfW_;
  float* gbias = (float*)pbias_;
  int*   deg   = (int*)pdeg_;
  int*   rp1   = (int*)prp1_;
  int*   rp2   = (int*)prp2_;
  int*   cur   = (int*)pcur_;
  int*   ps1   = (int*)pps1_;
  int*   ps2   = (int*)pps2_;
  int*   inv1  = (int*)pinv1_;
  int*   inv2  = (int*)pinv2_;
  int*   bsum  = (int*)pbs_;

  unsigned short* Wmega = bfW + 0;
  unsigned short* Wqs1  = bfW + 262144;
  unsigned short* Wkv2  = bfW + 393216;
  unsigned short* We1   = bfW + 524288;
  unsigned short* We2   = bfW + 557056;

  // Single-dispatch weight prep (5x wconv4 + bconcat merged).
  P20 P{{W1k, W1v, W2q, W2s, W1q, W1s, W2k, W2v, W1e, W2e},
        {b1k, b1v, b2q, b2s, b1q, b1s, b2k, b2v, b1e, b2e}};
  prep_weights<<<(592384 + 255) / 256, 256, 0, stream>>>(P, bfW, gbias);

  // token_x f32 -> bf16 (mega's A + ph2 residual).
  conv_bf16<<<(int)(((long long)NT * 32 + 255) / 256), 256, 0, stream>>>(
      token_x, bfA, (long long)NT * 32);

  const int e2grid = (2 * E + 255) / 256;

  // ---------------- CSR build (merged phases) ----------------
  hipMemsetAsync(deg, 0, (size_t)(2 * (NMAX + 1)) * sizeof(int), stream);
  hist2_kernel<<<e2grid, 256, 0, stream>>>(ei1, ei2, deg, E);
  {
    int B1 = (NR + 255) / 256;
    scan1<<<B1, 256, 0, stream>>>(deg, rp1, bsum, NR);
    scan2<<<1, 512, 0, stream>>>(bsum, B1);
    scan3<<<B1, 256, 0, stream>>>(rp1, bsum, deg, cur, NR);
    int B2 = (NT + 255) / 256;
    scan1<<<B2, 256, 0, stream>>>(deg + NMAX + 1, rp2, bsum, NT);
    scan2<<<1, 512, 0, stream>>>(bsum, B2);
    scan3<<<B2, 256, 0, stream>>>(rp2, bsum, deg + NMAX + 1, cur + NMAX, NT);
  }
  scatter2_kernel<<<e2grid, 256, 0, stream>>>(ei1, ei2, cur, ps1, ps2, inv1, inv2, E);

  // Swizzled 1-D grid size: ceil(nm/8)*8 * NC.
  auto swgrid = [](int M, int NC) {
    int nm = (M + 127) / 128;
    return (((nm + 7) / 8) * 8) * NC;
  };

  // ---------------- Projection GEMMs ----------------
  gemm_mfma<256, 1024, false><<<swgrid(NT, 8), 256, 0, stream>>>(
      bfA, Wmega, gbias + 0, mega, NT, nullptr);        // [k1|v1|q2|s2]
  gemm_mfma<256, 512, true><<<swgrid(NR, 4), 256, 0, stream>>>(
      row_x, Wqs1, gbias + 1024, qs, NR, nullptr);      // [q1|s1]
  gemm_mfma<128, 256, true><<<swgrid(E, 2), 256, 0, stream>>>(
      ea1, We1, gbias + 2048, eb1, E, inv1);            // CSR-slot order
  gemm_mfma<128, 256, true><<<swgrid(E, 2), 256, 0, stream>>>(
      ea2, We2, gbias + 2304, eb2, E, inv2);            // CSR-slot order

  // ---------------- Phase 1: t2r ----------------
  fused_attn_ln<<<(NR + 7) / 8, 256, 0, stream>>>(rp1, ps1,
                                                  qs, 512, mega, 1024, eb1,
                                                  row_x, nullptr,
                                                  row_gamma, row_beta,
                                                  out_row, bfB, NR);

  // ---------------- Phase 2: r2t ----------------
  gemm_mfma<256, 512, false><<<swgrid(NR, 4), 256, 0, stream>>>(
      bfB, Wkv2, gbias + 1536, kv, NR, nullptr);        // [k2|v2]
  fused_attn_ln<<<(NT + 7) / 8, 256, 0, stream>>>(rp2, ps2,
                                                  mega + 512, 1024, kv, 512, eb2,
                                                  nullptr, bfA,
                                                  token_gamma, token_beta,
                                                  out_tok, nullptr, NT);
}